// Round 13
// baseline (258.015 us; speedup 1.0000x reference)
//
#include <hip/hip_runtime.h>
#include <math.h>

#define B_    8
#define N_    8192
#define M_    65536        // B_*N_
#define I_    512
#define E_    8
#define D_    256
#define C_    10
#define NCLS_ 2

typedef unsigned short ushort_t;
typedef ushort_t ushortx8 __attribute__((ext_vector_type(8)));
typedef __bf16   bf16x8  __attribute__((ext_vector_type(8)));
typedef float    f32x4   __attribute__((ext_vector_type(4)));

// ---------------- workspace layout (byte offsets) ----------------
static const size_t XB_OFF   = 0;                         // bf16 x [M_,512] = 64 MB
static const size_t PS_OFF   = 67108864;                  // 8*M_*4 = 2 MB
static const size_t S_OFF    = PS_OFF + 2097152;          // M_*4
static const size_t PST_OFF  = S_OFF + 262144;            // 1280*4 = 5120
static const size_t CP_OFF   = PST_OFF + 5120;            // 512*10*512*4 = 10 MB
static const size_t CF2_OFF  = CP_OFF + 10485760;         // 80*512*4
static const size_t S2_OFF   = CF2_OFF + 163840;          // 512 B
static const size_t WFT_OFF  = S2_OFF + 512;              // bf16 [512][512]
static const size_t BAG_OFF  = WFT_OFF + 524288;          // bf16 [512][512]
static const size_t EMBW_OFF = BAG_OFF + 524288;          // f32 [10][512]

__device__ __forceinline__ float sigf(float v) { return 1.0f / (1.0f + __expf(-v)); }

__device__ __forceinline__ ushort_t f2bf(float f) {
    union { float f; unsigned u; } v; v.f = f;
    unsigned r = v.u + 0x7FFF + ((v.u >> 16) & 1);   // RNE (finite data)
    return (ushort_t)(r >> 16);
}
__device__ __forceinline__ float bf2f(ushort_t u) {
    union { unsigned u; float f; } v; v.u = ((unsigned)u) << 16; return v.f;
}

// async global->LDS, 16B per lane; LDS dest is wave-uniform base + lane*16
__device__ __forceinline__ void gl_lds16(const void* g, void* l) {
    __builtin_amdgcn_global_load_lds(
        (const __attribute__((address_space(1))) void*)g,
        (__attribute__((address_space(3))) void*)l, 16, 0, 0);
}

// counted waits (T4) + compiler fence
#define VMWAIT6 asm volatile("s_waitcnt vmcnt(6)" ::: "memory")
#define VMWAIT3 asm volatile("s_waitcnt vmcnt(3)" ::: "memory")
#define VMWAIT0 asm volatile("s_waitcnt vmcnt(0)" ::: "memory")
#define CFENCE  asm volatile("" ::: "memory")

// =====================================================================
// P: fused prep.
//   blocks [0,64):    WfT via LDS-tiled 64x64 transpose (both sides coalesced)
//   blocks [64,576):  BagT interleave of Wa/Wb
//   blocks [576,596): embW
// =====================================================================
__global__ __launch_bounds__(256) void prep_kernel(
    const float* __restrict__ Wf, const float* __restrict__ Wa,
    const float* __restrict__ Wb, const float* __restrict__ emb,
    const float* __restrict__ bfv,
    ushort_t* __restrict__ wft, ushort_t* __restrict__ bag,
    float* __restrict__ embW)
{
    __shared__ float tile[64][65];
    const int bid = blockIdx.x;
    const int t = threadIdx.x;
    if (bid < 64) {
        const int ti = bid >> 3, tj = bid & 7;    // k-tile, n-tile
#pragma unroll
        for (int i = 0; i < 16; ++i) {
            int kl = i * 4 + (t >> 6);            // 0..63
            int nl = t & 63;
            tile[nl][kl] = Wf[(size_t)(ti * 64 + kl) * 512 + tj * 64 + nl];
        }
        __syncthreads();
#pragma unroll
        for (int i = 0; i < 16; ++i) {
            int nl = i * 4 + (t >> 6);
            int kl = t & 63;
            wft[(size_t)(tj * 64 + nl) * 512 + ti * 64 + kl] = f2bf(tile[nl][kl]);
        }
    } else if (bid < 576) {
        int idx = (bid - 64) * 256 + t;           // (k, d)
        int k = idx >> 8, d = idx & 255;
        float a = Wa[(size_t)k * 256 + d];
        float g = Wb[(size_t)k * 256 + d];
        int blk = d >> 5, w = d & 31;
        bag[(size_t)(blk * 64 + w) * 512 + k]      = f2bf(a);
        bag[(size_t)(blk * 64 + 32 + w) * 512 + k] = f2bf(g);
    } else {
        int idx = (bid - 576) * 256 + t;          // < 5120
        int c = idx >> 9, n = idx & 511;
        float s = bfv[n];
#pragma unroll
        for (int e = 0; e < 8; ++e) s += emb[c * 8 + e] * Wf[(size_t)(512 + e) * 512 + n];
        embW[(size_t)c * 512 + n] = s;
    }
}

// =====================================================================
// K1: x = relu(h@Wf[:512] + embW[cid]) -> bf16, fused f32 input.
// NEW: BM=128 x BN=128, BK=32, 256 thr = 4 waves (2x2), wave tile 64x64.
// 3-buffer counted-vmcnt single-barrier schedule (the R11/R12-proven
// gemm_ag pattern) at 72 KB LDS -> 2 blocks/CU.  6 VMEM ops/tile/wave
// (4 A f32 + 2 B bf16) -> steady-state vmcnt(6), 2-deep prefetch.
// Hazards: RAW via per-wave counted vmcnt before the barrier (uniform
// issue counts); WAR via data dependence (kt-1 ds_reads feed kt-1 MFMAs
// whose lgkm waits precede the kt barrier).
// =====================================================================
__global__ __launch_bounds__(256) void gemm_x_mfma(
    const float* __restrict__ hf, const int* __restrict__ cid,
    const ushort_t* __restrict__ wft, const float* __restrict__ embW,
    ushort_t* __restrict__ xb)
{
    __shared__ float    Asf[3][128 * 32];   // 48 KB (f32 A tiles; reused as out-stage)
    __shared__ ushort_t Bs[3][128 * 32];    // 24 KB

    const int t = threadIdx.x;
    // XCD-aware bijective swizzle (nwg = 2048 = 8*256)
    const int lin = blockIdx.y * 4 + blockIdx.x;
    const int swz = (lin & 7) * 256 + (lin >> 3);
    const int n0 = (swz & 3) * 128;
    const int m0 = (swz >> 2) * 128;

    const int wid = t >> 6;                 // 0..3
    const int wr = wid >> 1, wc = wid & 1;  // 2M x 2N wave grid
    const int l = t & 63, lr = l & 15, lg = l >> 4;

    // ---- B staging (gload_lds, bf16): wave wid stages rows [wid*32, wid*32+32)
    // in two 16-row ops (each: lane covers row l>>2, chunk l&3 of 4x16B).
    const int srow = l >> 2;
    const int gchB = ((l & 3) ^ ((l >> 3) & 3)) * 8;
    const size_t gB0 = (size_t)(n0 + wid * 32 + srow) * 512 + gchB;
    const size_t gB1 = gB0 + 16 * 512;

    // ---- A staging (gload_lds, f32): wave wid stages rows [wid*32, wid*32+32)
    // in four 8-row ops (lane covers row l>>3, phys chunk l&7, pre-swizzled src).
    const int ArowL = wid * 32 + (l >> 3);
    const int gchA  = ((l & 7) ^ ((l >> 3) & 7)) * 4;          // f32 offset
    const size_t gAf = (size_t)(m0 + ArowL) * 512 + gchA;

    f32x4 acc[4][4] = {};

#define STAGE_X(buf, kt) do { \
    size_t ko = (size_t)(kt) * 32; \
    char* aB = (char*)&Asf[buf][0] + wid * 4096; \
    gl_lds16(hf + gAf + ko,            aB); \
    gl_lds16(hf + gAf + ko +  8 * 512, aB + 1024); \
    gl_lds16(hf + gAf + ko + 16 * 512, aB + 2048); \
    gl_lds16(hf + gAf + ko + 24 * 512, aB + 3072); \
    gl_lds16(wft + gB0 + ko, &Bs[buf][wid * 1024]); \
    gl_lds16(wft + gB1 + ko, &Bs[buf][wid * 1024 + 512]); \
} while (0)

    STAGE_X(0, 0);
    STAGE_X(1, 1);
    for (int kt = 0; kt < 16; ++kt) {
        if (kt < 15) { VMWAIT6; } else { VMWAIT0; }   // tile kt landed (all waves: barrier)
        __builtin_amdgcn_s_barrier();
        CFENCE;
        if (kt + 2 < 16) STAGE_X((kt + 2) % 3, kt + 2);
        const float* Aw = &Asf[kt % 3][0];
        const char*  Bb = (const char*)&Bs[kt % 3][0];
        bf16x8 af[4], bg[4];
#pragma unroll
        for (int mi = 0; mi < 4; ++mi) {
            int R = wr * 64 + mi * 16 + lr;
            const float* Arow = Aw + R * 32;
            int s7 = R & 7;
            f32x4 lo = *(const f32x4*)(Arow + (((2 * lg)     ^ s7) << 2));
            f32x4 hi = *(const f32x4*)(Arow + (((2 * lg + 1) ^ s7) << 2));
            bf16x8 a;
            a[0] = (__bf16)lo[0]; a[1] = (__bf16)lo[1];
            a[2] = (__bf16)lo[2]; a[3] = (__bf16)lo[3];
            a[4] = (__bf16)hi[0]; a[5] = (__bf16)hi[1];
            a[6] = (__bf16)hi[2]; a[7] = (__bf16)hi[3];
            af[mi] = a;
        }
#pragma unroll
        for (int ni = 0; ni < 4; ++ni) {
            int Cc = wc * 64 + ni * 16 + lr;
            bg[ni] = *(const bf16x8*)(Bb + Cc * 64 + ((lg ^ ((Cc >> 1) & 3)) << 4));
        }
#pragma unroll
        for (int mi = 0; mi < 4; ++mi)
#pragma unroll
            for (int ni = 0; ni < 4; ++ni)
                acc[mi][ni] = __builtin_amdgcn_mfma_f32_16x16x32_bf16(af[mi], bg[ni], acc[mi][ni], 0, 0, 0);
    }
    __syncthreads();   // all waves done reading LDS before out-stage reuse

    // epilogue: + embW, relu, stage bf16 tile in Asf (dead), coalesced store
    ushort_t* sc = (ushort_t*)&Asf[0][0];   // [128][128] bf16 = 32 KB
#pragma unroll
    for (int mi = 0; mi < 4; ++mi) {
#pragma unroll
        for (int r = 0; r < 4; ++r) {
            int row = wr * 64 + mi * 16 + lg * 4 + r;            // block-local
            const float* ew = embW + (size_t)cid[m0 + row] * 512;
#pragma unroll
            for (int ni = 0; ni < 4; ++ni) {
                int col = wc * 64 + ni * 16 + lr;                // block-local
                float v = acc[mi][ni][r] + ew[n0 + col];
                sc[row * 128 + col] = f2bf(fmaxf(v, 0.0f));
            }
        }
    }
    __syncthreads();
    {
        const int cch = t & 15;
        const int r0  = t >> 4;        // 0..15
#pragma unroll
        for (int j = 0; j < 8; ++j) {
            int row = r0 + j * 16;
            *(ushortx8*)(xb + (size_t)(m0 + row) * 512 + n0 + cch * 8) =
                *(const ushortx8*)(sc + row * 128 + cch * 8);
        }
    }
}

// =====================================================================
// K2: gated attention partial scores — R11/R12-proven 3-buffer counted
// schedule (3 VMEM ops/tile/wave -> vmcnt(3)).  72 KB LDS -> 2 blocks/CU.
// =====================================================================
__global__ __launch_bounds__(512) void gemm_ag_mfma(
    const ushort_t* __restrict__ xb, const ushort_t* __restrict__ bag,
    const float* __restrict__ bav, const float* __restrict__ bbv,
    const float* __restrict__ Wc, float* __restrict__ ps)
{
    __shared__ ushort_t As[3][256 * 32];   // 48 KB
    __shared__ ushort_t Bs[3][128 * 32];   // 24 KB

    const int t = threadIdx.x;
    const int lin = blockIdx.y * 4 + blockIdx.x;
    const int swz = (lin & 7) * 128 + (lin >> 3);
    const int bxn = swz & 3;
    const int n0 = bxn * 128;
    const int m0 = (swz >> 2) * 256;

    const int wid = t >> 6;
    const int wr = wid >> 1, wc = wid & 1;
    const int l = t & 63, lr = l & 15, lg = l >> 4;

    const int srow = l >> 2;
    const int gch  = ((l & 3) ^ ((l >> 3) & 3)) * 8;

    const size_t gA0 = (size_t)(m0 + wid * 32 + srow) * 512 + gch;
    const size_t gA1 = gA0 + 16 * 512;
    const size_t gB0 = (size_t)(n0 + wid * 16 + srow) * 512 + gch;

    f32x4 acc[4][4] = {};

#define STAGE_AG(buf, kt) do { \
    size_t ko = (size_t)(kt) * 32; \
    gl_lds16(xb + gA0 + ko,  &As[buf][wid * 1024]); \
    gl_lds16(xb + gA1 + ko,  &As[buf][wid * 1024 + 512]); \
    gl_lds16(bag + gB0 + ko, &Bs[buf][wid * 512]); \
} while (0)

    STAGE_AG(0, 0);
    STAGE_AG(1, 1);
    for (int kt = 0; kt < 16; ++kt) {
        if (kt < 15) { VMWAIT3; } else { VMWAIT0; }
        __builtin_amdgcn_s_barrier();
        CFENCE;
        if (kt + 2 < 16) STAGE_AG((kt + 2) % 3, kt + 2);
        const char* Ab = (const char*)&As[kt % 3][0];
        const char* Bb = (const char*)&Bs[kt % 3][0];
        bf16x8 af[4], bg[4];
#pragma unroll
        for (int mi = 0; mi < 4; ++mi) {
            int R = wr * 64 + mi * 16 + lr;
            af[mi] = *(const bf16x8*)(Ab + R * 64 + ((lg ^ ((R >> 1) & 3)) << 4));
        }
#pragma unroll
        for (int ni = 0; ni < 4; ++ni) {
            int Cc = wc * 64 + ni * 16 + lr;
            bg[ni] = *(const bf16x8*)(Bb + Cc * 64 + ((lg ^ ((Cc >> 1) & 3)) << 4));
        }
#pragma unroll
        for (int mi = 0; mi < 4; ++mi)
#pragma unroll
            for (int ni = 0; ni < 4; ++ni)
                acc[mi][ni] = __builtin_amdgcn_mfma_f32_16x16x32_bf16(af[mi], bg[ni], acc[mi][ni], 0, 0, 0);
    }

    const int blk = bxn * 2 + wc;                 // 0..7
    const int d0 = blk * 32 + lr, d1 = d0 + 16;
    const float ba0 = bav[d0], ba1 = bav[d1];
    const float bb0 = bbv[d0], bb1 = bbv[d1];
    const float w0 = Wc[d0],  w1 = Wc[d1];

#pragma unroll
    for (int mi = 0; mi < 4; ++mi) {
#pragma unroll
        for (int r = 0; r < 4; ++r) {
            float p = tanhf(acc[mi][0][r] + ba0) * sigf(acc[mi][2][r] + bb0) * w0
                    + tanhf(acc[mi][1][r] + ba1) * sigf(acc[mi][3][r] + bb1) * w1;
            p += __shfl_xor(p, 1); p += __shfl_xor(p, 2);
            p += __shfl_xor(p, 4); p += __shfl_xor(p, 8);
            if (lr == 0)
                ps[(size_t)blk * M_ + m0 + wr * 64 + mi * 16 + lg * 4 + r] = p;
        }
    }
}

// =====================================================================
// K3: fused s-combine + per-slice segmented stats (proven).
// =====================================================================
__global__ __launch_bounds__(256) void sstats_kernel(
    const float* __restrict__ ps, const float* __restrict__ bc,
    const int* __restrict__ cid, float* __restrict__ S,
    float* __restrict__ pst)
{
    __shared__ float redm[4][C_];
    __shared__ float smx[C_];
    __shared__ float reds[4][C_];

    const int b  = blockIdx.x >> 3;
    const int sl = blockIdx.x & 7;
    const int bs = blockIdx.x;
    const int t  = threadIdx.x;
    const int l  = t & 63, wv = t >> 6;
    const int base = b * N_ + sl * 1024;

    float sv[4]; int cv[4];
#pragma unroll
    for (int i = 0; i < 4; ++i) {
        int m = base + i * 256 + t;
        float v = bc[0];
#pragma unroll
        for (int k = 0; k < 8; ++k) v += ps[(size_t)k * M_ + m];
        S[m] = v; sv[i] = v; cv[i] = cid[m];
    }

    float mx[C_];
#pragma unroll
    for (int c = 0; c < C_; ++c) mx[c] = -3.0e38f;
#pragma unroll
    for (int i = 0; i < 4; ++i)
#pragma unroll
        for (int c = 0; c < C_; ++c)
            mx[c] = fmaxf(mx[c], (cv[i] == c) ? sv[i] : -3.0e38f);
#pragma unroll
    for (int c = 0; c < C_; ++c) {
        float v = mx[c];
        v = fmaxf(v, __shfl_xor(v, 32)); v = fmaxf(v, __shfl_xor(v, 16));
        v = fmaxf(v, __shfl_xor(v, 8));  v = fmaxf(v, __shfl_xor(v, 4));
        v = fmaxf(v, __shfl_xor(v, 2));  v = fmaxf(v, __shfl_xor(v, 1));
        if (l == 0) redm[wv][c] = v;
    }
    __syncthreads();
    if (t < C_)
        smx[t] = fmaxf(fmaxf(redm[0][t], redm[1][t]), fmaxf(redm[2][t], redm[3][t]));
    __syncthreads();

    float sm[C_];
#pragma unroll
    for (int c = 0; c < C_; ++c) sm[c] = 0.f;
#pragma unroll
    for (int i = 0; i < 4; ++i) {
        float e = expf(sv[i] - smx[cv[i]]);
#pragma unroll
        for (int c = 0; c < C_; ++c) sm[c] += (cv[i] == c) ? e : 0.f;
    }
#pragma unroll
    for (int c = 0; c < C_; ++c) {
        float v = sm[c];
        v += __shfl_xor(v, 32); v += __shfl_xor(v, 16); v += __shfl_xor(v, 8);
        v += __shfl_xor(v, 4);  v += __shfl_xor(v, 2);  v += __shfl_xor(v, 1);
        if (l == 0) reds[wv][c] = v;
    }
    __syncthreads();
    if (t < C_) {
        pst[bs * C_ + t]       = smx[t];
        pst[640 + bs * C_ + t] = reds[0][t] + reds[1][t] + reds[2][t] + reds[3][t];
    }
}

// =====================================================================
// K4: segmented weighted sums; per-(b,c) stats recomputed in-block.
// =====================================================================
__global__ __launch_bounds__(256) void cpart_kernel(
    const ushort_t* __restrict__ xb, const int* __restrict__ cid,
    const float* __restrict__ s, const float* __restrict__ pst,
    float* __restrict__ cpart)
{
    __shared__ float smax[C_], sinv[C_];
    __shared__ float wrow[128];
    __shared__ int   crow[128];
    const int b     = blockIdx.x >> 6;
    const int chunk = blockIdx.x & 63;
    const int t     = threadIdx.x;
    const int base  = b * N_ + chunk * 128;

    if (t < C_) {
        float mxv = -3.0e38f;
#pragma unroll
        for (int sl = 0; sl < 8; ++sl)
            mxv = fmaxf(mxv, pst[(b * 8 + sl) * C_ + t]);
        float sum = 0.f;
#pragma unroll
        for (int sl = 0; sl < 8; ++sl)
            sum += pst[640 + (b * 8 + sl) * C_ + t] * expf(pst[(b * 8 + sl) * C_ + t] - mxv);
        smax[t] = mxv;
        sinv[t] = 1.0f / sum;
    }
    __syncthreads();
    if (t < 128) {
        int m = base + t;
        int c = cid[m];
        crow[t] = c;
        wrow[t] = expf(s[m] - smax[c]) * sinv[c];
    }
    __syncthreads();

    float2 acc[C_];
#pragma unroll
    for (int c = 0; c < C_; ++c) { acc[c].x = 0.f; acc[c].y = 0.f; }

    for (int r = 0; r < 128; ++r) {
        int c = crow[r];
        float wv = wrow[r];
        unsigned xv = *(const unsigned*)(xb + (size_t)(base + r) * 512 + t * 2);
        float x0 = bf2f((ushort_t)(xv & 0xffff));
        float x1 = bf2f((ushort_t)(xv >> 16));
#pragma unroll
        for (int cc = 0; cc < C_; ++cc) {
            float w = (cc == c) ? wv : 0.0f;
            acc[cc].x += w * x0;
            acc[cc].y += w * x1;
        }
    }
#pragma unroll
    for (int cc = 0; cc < C_; ++cc)
        *(float2*)(&cpart[(((size_t)blockIdx.x) * C_ + cc) * 512 + t * 2]) = acc[cc];
}

// =====================================================================
// K5: chunk-reduce + intra fc + inter score (proven).
// =====================================================================
__global__ __launch_bounds__(256) void intra_inter_kernel(
    const float* __restrict__ cpart, const float* __restrict__ Wfc,
    const float* __restrict__ bfc,
    const float* __restrict__ Wa2, const float* __restrict__ ba2,
    const float* __restrict__ Wb2, const float* __restrict__ bb2,
    const float* __restrict__ Wc2, const float* __restrict__ bc2,
    float* __restrict__ cfeat2, float* __restrict__ s2)
{
    __shared__ float row[512];
    __shared__ float row2[512];
    __shared__ float red[256];
    const int bc = blockIdx.x;
    const int b = bc / C_, c = bc % C_;
    const int t  = threadIdx.x;

    float r0 = 0.f, r1 = 0.f;
    for (int ch = 0; ch < 64; ++ch) {
        size_t o = (((size_t)(b * 64 + ch)) * C_ + c) * 512;
        r0 += cpart[o + t];
        r1 += cpart[o + 256 + t];
    }
    row[t] = r0; row[t + 256] = r1;
    __syncthreads();

    float a0 = 0.f, a1 = 0.f;
    for (int i = 0; i < 512; ++i) {
        float rv = row[i];
        a0 += rv * Wfc[(size_t)i * 512 + t];
        a1 += rv * Wfc[(size_t)i * 512 + 256 + t];
    }
    a0 = fmaxf(a0 + bfc[t], 0.f);
    a1 = fmaxf(a1 + bfc[256 + t], 0.f);
    cfeat2[bc * 512 + t]       = a0;
    cfeat2[bc * 512 + 256 + t] = a1;
    row2[t] = a0; row2[t + 256] = a1;
    __syncthreads();

    float pa = 0.f, pg = 0.f;
    for (int f = 0; f < 512; ++f) {
        float rv = row2[f];
        pa += rv * Wa2[(size_t)f * 256 + t];
        pg += rv * Wb2[(size_t)f * 256 + t];
    }
    float v = tanhf(pa + ba2[t]) * sigf(pg + bb2[t]) * Wc2[t];
    red[t] = v; __syncthreads();
    for (int off = 128; off > 0; off >>= 1) {
        if (t < off) red[t] += red[t + off];
        __syncthreads();
    }
    if (t == 0) s2[bc] = red[0] + bc2[0];
}

// K6: softmax over C, slide pooling, final fc + classifier
__global__ __launch_bounds__(256) void final_kernel(
    const float* __restrict__ cfeat2, const float* __restrict__ s2,
    const float* __restrict__ Wfc2, const float* __restrict__ bfc2,
    const float* __restrict__ Wcls, const float* __restrict__ bcls,
    float* __restrict__ out)
{
    __shared__ float A2[C_];
    __shared__ float slide[512];
    __shared__ float slide2[256];
    const int b = blockIdx.x;
    const int t = threadIdx.x;

    if (t < C_) A2[t] = s2[b * C_ + t];
    __syncthreads();
    float mx = -3.0e38f;
    for (int c = 0; c < C_; ++c) mx = fmaxf(mx, A2[c]);
    float sum = 0.f;
    for (int c = 0; c < C_; ++c) sum += expf(A2[c] - mx);
    __syncthreads();
    if (t < C_) A2[t] = expf(A2[t] - mx) / sum;
    __syncthreads();

    float s0 = 0.f, s1 = 0.f;
    for (int c = 0; c < C_; ++c) {
        float a = A2[c];
        s0 += a * cfeat2[(b * C_ + c) * 512 + t];
        s1 += a * cfeat2[(b * C_ + c) * 512 + 256 + t];
    }
    slide[t] = s0; slide[t + 256] = s1;
    __syncthreads();

    float acc = 0.f;
    for (int f = 0; f < 512; ++f) acc += slide[f] * Wfc2[(size_t)f * 256 + t];
    slide2[t] = fmaxf(acc + bfc2[t], 0.f);
    __syncthreads();

    if (t < NCLS_) {
        float lg = bcls[t];
        for (int o = 0; o < 256; ++o) lg += slide2[o] * Wcls[o * 2 + t];
        out[b * 2 + t] = lg;
    }
}

extern "C" void kernel_launch(void* const* d_in, const int* in_sizes, int n_in,
                              void* d_out, int out_size, void* d_ws, size_t ws_size,
                              hipStream_t stream)
{
    (void)in_sizes; (void)n_in; (void)out_size; (void)ws_size;
    const float* h    = (const float*)d_in[0];
    const int*   cid  = (const int*)  d_in[1];
    const float* emb  = (const float*)d_in[2];
    const float* Wf   = (const float*)d_in[3];
    const float* bf   = (const float*)d_in[4];
    const float* Wa   = (const float*)d_in[5];
    const float* ba   = (const float*)d_in[6];
    const float* Wb   = (const float*)d_in[7];
    const float* bb   = (const float*)d_in[8];
    const float* Wc   = (const float*)d_in[9];
    const float* bc   = (const float*)d_in[10];
    const float* Wfc  = (const float*)d_in[11];
    const float* bfc  = (const float*)d_in[12];
    const float* Wa2  = (const float*)d_in[13];
    const float* ba2  = (const float*)d_in[14];
    const float* Wb2  = (const float*)d_in[15];
    const float* bb2  = (const float*)d_in[16];
    const float* Wc2  = (const float*)d_in[17];
    const float* bc2  = (const float*)d_in[18];
    const float* Wfc2 = (const float*)d_in[19];
    const float* bfc2 = (const float*)d_in[20];
    const float* Wcls = (const float*)d_in[21];
    const float* bcls = (const float*)d_in[22];

    char* ws = (char*)d_ws;
    ushort_t* XB   = (ushort_t*)(ws + XB_OFF);
    float* PS      = (float*)(ws + PS_OFF);
    float* S       = (float*)(ws + S_OFF);
    float* PST     = (float*)(ws + PST_OFF);
    float* CPART   = (float*)(ws + CP_OFF);
    float* CFEAT2  = (float*)(ws + CF2_OFF);
    float* S2      = (float*)(ws + S2_OFF);
    ushort_t* WFT  = (ushort_t*)(ws + WFT_OFF);
    ushort_t* BAG  = (ushort_t*)(ws + BAG_OFF);
    float* EMBW    = (float*)(ws + EMBW_OFF);
    float* out     = (float*)d_out;

    prep_kernel<<<596, 256, 0, stream>>>(Wf, Wa, Wb, emb, bf, WFT, BAG, EMBW);

    gemm_x_mfma<<<dim3(4, 512), 256, 0, stream>>>(h, cid, WFT, EMBW, XB);
    gemm_ag_mfma<<<dim3(4, 256), 512, 0, stream>>>(XB, BAG, ba, bb, Wc, PS);

    sstats_kernel<<<64, 256, 0, stream>>>(PS, bc, cid, S, PST);
    cpart_kernel<<<512, 256, 0, stream>>>(XB, cid, S, PST, CPART);
    intra_inter_kernel<<<B_ * C_, 256, 0, stream>>>(CPART, Wfc, bfc,
                                                    Wa2, ba2, Wb2, bb2, Wc2, bc2,
                                                    CFEAT2, S2);
    final_kernel<<<B_, 256, 0, stream>>>(CFEAT2, S2, Wfc2, bfc2, Wcls, bcls, out);
}

// Round 14
// 205.588 us; speedup vs baseline: 1.2550x; 1.2550x over previous
//
#include <hip/hip_runtime.h>
#include <math.h>

#define B_    8
#define N_    8192
#define M_    65536        // B_*N_
#define I_    512
#define E_    8
#define D_    256
#define C_    10
#define NCLS_ 2

typedef unsigned short ushort_t;
typedef ushort_t ushortx8 __attribute__((ext_vector_type(8)));
typedef __bf16   bf16x8  __attribute__((ext_vector_type(8)));
typedef float    f32x4   __attribute__((ext_vector_type(4)));

// ---------------- workspace layout (byte offsets) ----------------
static const size_t XB_OFF   = 0;                         // bf16 x [M_,512] = 64 MB
static const size_t PS_OFF   = 67108864;                  // 8*M_*4 = 2 MB
static const size_t S_OFF    = PS_OFF + 2097152;          // M_*4
static const size_t PST_OFF  = S_OFF + 262144;            // 1280*4 = 5120
static const size_t CP_OFF   = PST_OFF + 5120;            // 512*10*512*4 = 10 MB
static const size_t CF2_OFF  = CP_OFF + 10485760;         // 80*512*4
static const size_t S2_OFF   = CF2_OFF + 163840;          // 512 B
static const size_t WFT_OFF  = S2_OFF + 512;              // bf16 [512][512]
static const size_t BAG_OFF  = WFT_OFF + 524288;          // bf16 [512][512]
static const size_t EMBW_OFF = BAG_OFF + 524288;          // f32 [10][512]

__device__ __forceinline__ float sigf(float v) { return 1.0f / (1.0f + __expf(-v)); }

__device__ __forceinline__ ushort_t f2bf(float f) {
    union { float f; unsigned u; } v; v.f = f;
    unsigned r = v.u + 0x7FFF + ((v.u >> 16) & 1);   // RNE (finite data)
    return (ushort_t)(r >> 16);
}
__device__ __forceinline__ float bf2f(ushort_t u) {
    union { unsigned u; float f; } v; v.u = ((unsigned)u) << 16; return v.f;
}

// async global->LDS, 16B per lane; LDS dest is wave-uniform base + lane*16
__device__ __forceinline__ void gl_lds16(const void* g, void* l) {
    __builtin_amdgcn_global_load_lds(
        (const __attribute__((address_space(1))) void*)g,
        (__attribute__((address_space(3))) void*)l, 16, 0, 0);
}

// counted waits (T4) + compiler fence
#define VMWAIT3 asm volatile("s_waitcnt vmcnt(3)" ::: "memory")
#define VMWAIT0 asm volatile("s_waitcnt vmcnt(0)" ::: "memory")
#define CFENCE  asm volatile("" ::: "memory")

// =====================================================================
// P: fused prep.
//   blocks [0,64):    WfT via LDS-tiled 64x64 transpose (both sides coalesced)
//   blocks [64,576):  BagT interleave of Wa/Wb
//   blocks [576,596): embW
// =====================================================================
__global__ __launch_bounds__(256) void prep_kernel(
    const float* __restrict__ Wf, const float* __restrict__ Wa,
    const float* __restrict__ Wb, const float* __restrict__ emb,
    const float* __restrict__ bfv,
    ushort_t* __restrict__ wft, ushort_t* __restrict__ bag,
    float* __restrict__ embW)
{
    __shared__ float tile[64][65];
    const int bid = blockIdx.x;
    const int t = threadIdx.x;
    if (bid < 64) {
        const int ti = bid >> 3, tj = bid & 7;    // k-tile, n-tile
#pragma unroll
        for (int i = 0; i < 16; ++i) {
            int kl = i * 4 + (t >> 6);            // 0..63
            int nl = t & 63;
            tile[nl][kl] = Wf[(size_t)(ti * 64 + kl) * 512 + tj * 64 + nl];
        }
        __syncthreads();
#pragma unroll
        for (int i = 0; i < 16; ++i) {
            int nl = i * 4 + (t >> 6);
            int kl = t & 63;
            wft[(size_t)(tj * 64 + nl) * 512 + ti * 64 + kl] = f2bf(tile[nl][kl]);
        }
    } else if (bid < 576) {
        int idx = (bid - 64) * 256 + t;           // (k, d)
        int k = idx >> 8, d = idx & 255;
        float a = Wa[(size_t)k * 256 + d];
        float g = Wb[(size_t)k * 256 + d];
        int blk = d >> 5, w = d & 31;
        bag[(size_t)(blk * 64 + w) * 512 + k]      = f2bf(a);
        bag[(size_t)(blk * 64 + 32 + w) * 512 + k] = f2bf(g);
    } else {
        int idx = (bid - 576) * 256 + t;          // < 5120
        int c = idx >> 9, n = idx & 511;
        float s = bfv[n];
#pragma unroll
        for (int e = 0; e < 8; ++e) s += emb[c * 8 + e] * Wf[(size_t)(512 + e) * 512 + n];
        embW[(size_t)c * 512 + n] = s;
    }
}

// =====================================================================
// K1: x = relu(h@Wf[:512] + embW[cid]) -> bf16, fused f32 input.
// R12-proven (100us): BM=256 x BN=128, BK=32, 512 thr = 8 waves (4x2),
// 2-buffer, one __syncthreads per kt, 80 KB LDS -> 2 blocks/CU.
// =====================================================================
__global__ __launch_bounds__(512) void gemm_x_mfma(
    const float* __restrict__ hf, const int* __restrict__ cid,
    const ushort_t* __restrict__ wft, const float* __restrict__ embW,
    ushort_t* __restrict__ xb)
{
    __shared__ float    Asf[2][256 * 32];   // 64 KB (f32 A tiles; reused as out-stage)
    __shared__ ushort_t Bs[2][128 * 32];    // 16 KB

    const int t = threadIdx.x;
    // XCD-aware bijective swizzle (nwg = 1024 = 8*128)
    const int lin = blockIdx.y * 4 + blockIdx.x;
    const int swz = (lin & 7) * 128 + (lin >> 3);
    const int n0 = (swz & 3) * 128;
    const int m0 = (swz >> 2) * 256;

    const int wid = t >> 6;                 // 0..7
    const int wr = wid >> 1, wc = wid & 1;  // 4M x 2N wave grid
    const int l = t & 63, lr = l & 15, lg = l >> 4;

    // ---- B staging (gload_lds, bf16): wave wid stages rows [wid*16, wid*16+16)
    const int srow = l >> 2;
    const int gchB = ((l & 3) ^ ((l >> 3) & 3)) * 8;
    const size_t gB0 = (size_t)(n0 + wid * 16 + srow) * 512 + gchB;
    ushort_t* lB = &Bs[0][wid * 512];

    // ---- A staging (gload_lds, f32): wave wid stages rows [wid*32, wid*32+32)
    const int ArowL = wid * 32 + (l >> 3);
    const int gchA  = ((l & 7) ^ ((l >> 3) & 7)) * 4;          // f32 offset
    const size_t gAf = (size_t)(m0 + ArowL) * 512 + gchA;

    f32x4 acc[4][4] = {};

#define STAGE_X(buf, kt) do { \
    size_t ko = (size_t)(kt) * 32; \
    char* aB = (char*)&Asf[buf][0] + wid * 4096; \
    gl_lds16(hf + gAf + ko,            aB); \
    gl_lds16(hf + gAf + ko +  8 * 512, aB + 1024); \
    gl_lds16(hf + gAf + ko + 16 * 512, aB + 2048); \
    gl_lds16(hf + gAf + ko + 24 * 512, aB + 3072); \
    gl_lds16(wft + gB0 + ko, lB + (buf) * 4096); \
} while (0)

    STAGE_X(0, 0);
    __syncthreads();
    int cur = 0;
    for (int kt = 0; kt < 16; ++kt) {
        if (kt < 15) STAGE_X(cur ^ 1, kt + 1);
        const float* Aw = &Asf[cur][0];
        const char*  Bb = (const char*)&Bs[cur][0];
        bf16x8 af[4], bg[4];
#pragma unroll
        for (int mi = 0; mi < 4; ++mi) {
            int R = wr * 64 + mi * 16 + lr;
            const float* Arow = Aw + R * 32;
            int s7 = R & 7;
            f32x4 lo = *(const f32x4*)(Arow + (((2 * lg)     ^ s7) << 2));
            f32x4 hi = *(const f32x4*)(Arow + (((2 * lg + 1) ^ s7) << 2));
            bf16x8 a;
            a[0] = (__bf16)lo[0]; a[1] = (__bf16)lo[1];
            a[2] = (__bf16)lo[2]; a[3] = (__bf16)lo[3];
            a[4] = (__bf16)hi[0]; a[5] = (__bf16)hi[1];
            a[6] = (__bf16)hi[2]; a[7] = (__bf16)hi[3];
            af[mi] = a;
        }
#pragma unroll
        for (int ni = 0; ni < 4; ++ni) {
            int Cc = wc * 64 + ni * 16 + lr;
            bg[ni] = *(const bf16x8*)(Bb + Cc * 64 + ((lg ^ ((Cc >> 1) & 3)) << 4));
        }
#pragma unroll
        for (int mi = 0; mi < 4; ++mi)
#pragma unroll
            for (int ni = 0; ni < 4; ++ni)
                acc[mi][ni] = __builtin_amdgcn_mfma_f32_16x16x32_bf16(af[mi], bg[ni], acc[mi][ni], 0, 0, 0);
        __syncthreads();   // implicit vmcnt(0): next tile staged & visible
        cur ^= 1;
    }

    // epilogue: + embW, relu, stage bf16 tile in Asf (dead), coalesced store
    ushort_t* sc = (ushort_t*)&Asf[0][0];   // [256][128] bf16 = 64 KB
#pragma unroll
    for (int mi = 0; mi < 4; ++mi) {
#pragma unroll
        for (int r = 0; r < 4; ++r) {
            int row = wr * 64 + mi * 16 + lg * 4 + r;            // block-local
            const float* ew = embW + (size_t)cid[m0 + row] * 512;
#pragma unroll
            for (int ni = 0; ni < 4; ++ni) {
                int col = wc * 64 + ni * 16 + lr;                // block-local
                float v = acc[mi][ni][r] + ew[n0 + col];
                sc[row * 128 + col] = f2bf(fmaxf(v, 0.0f));
            }
        }
    }
    __syncthreads();
    {
        const int cch = t & 15;
        const int r0  = t >> 4;
#pragma unroll
        for (int j = 0; j < 8; ++j) {
            int row = r0 + j * 32;
            *(ushortx8*)(xb + (size_t)(m0 + row) * 512 + n0 + cch * 8) =
                *(const ushortx8*)(sc + row * 128 + cch * 8);
        }
    }
}

// =====================================================================
// K2: gated attention partial scores — R11/R12-proven 3-buffer counted
// schedule (3 VMEM ops/tile/wave -> vmcnt(3)).  72 KB LDS -> 2 blocks/CU.
// =====================================================================
__global__ __launch_bounds__(512) void gemm_ag_mfma(
    const ushort_t* __restrict__ xb, const ushort_t* __restrict__ bag,
    const float* __restrict__ bav, const float* __restrict__ bbv,
    const float* __restrict__ Wc, float* __restrict__ ps)
{
    __shared__ ushort_t As[3][256 * 32];   // 48 KB
    __shared__ ushort_t Bs[3][128 * 32];   // 24 KB

    const int t = threadIdx.x;
    const int lin = blockIdx.y * 4 + blockIdx.x;
    const int swz = (lin & 7) * 128 + (lin >> 3);
    const int bxn = swz & 3;
    const int n0 = bxn * 128;
    const int m0 = (swz >> 2) * 256;

    const int wid = t >> 6;
    const int wr = wid >> 1, wc = wid & 1;
    const int l = t & 63, lr = l & 15, lg = l >> 4;

    const int srow = l >> 2;
    const int gch  = ((l & 3) ^ ((l >> 3) & 3)) * 8;

    const size_t gA0 = (size_t)(m0 + wid * 32 + srow) * 512 + gch;
    const size_t gA1 = gA0 + 16 * 512;
    const size_t gB0 = (size_t)(n0 + wid * 16 + srow) * 512 + gch;

    f32x4 acc[4][4] = {};

#define STAGE_AG(buf, kt) do { \
    size_t ko = (size_t)(kt) * 32; \
    gl_lds16(xb + gA0 + ko,  &As[buf][wid * 1024]); \
    gl_lds16(xb + gA1 + ko,  &As[buf][wid * 1024 + 512]); \
    gl_lds16(bag + gB0 + ko, &Bs[buf][wid * 512]); \
} while (0)

    STAGE_AG(0, 0);
    STAGE_AG(1, 1);
    for (int kt = 0; kt < 16; ++kt) {
        if (kt < 15) { VMWAIT3; } else { VMWAIT0; }
        __builtin_amdgcn_s_barrier();
        CFENCE;
        if (kt + 2 < 16) STAGE_AG((kt + 2) % 3, kt + 2);
        const char* Ab = (const char*)&As[kt % 3][0];
        const char* Bb = (const char*)&Bs[kt % 3][0];
        bf16x8 af[4], bg[4];
#pragma unroll
        for (int mi = 0; mi < 4; ++mi) {
            int R = wr * 64 + mi * 16 + lr;
            af[mi] = *(const bf16x8*)(Ab + R * 64 + ((lg ^ ((R >> 1) & 3)) << 4));
        }
#pragma unroll
        for (int ni = 0; ni < 4; ++ni) {
            int Cc = wc * 64 + ni * 16 + lr;
            bg[ni] = *(const bf16x8*)(Bb + Cc * 64 + ((lg ^ ((Cc >> 1) & 3)) << 4));
        }
#pragma unroll
        for (int mi = 0; mi < 4; ++mi)
#pragma unroll
            for (int ni = 0; ni < 4; ++ni)
                acc[mi][ni] = __builtin_amdgcn_mfma_f32_16x16x32_bf16(af[mi], bg[ni], acc[mi][ni], 0, 0, 0);
    }

    const int blk = bxn * 2 + wc;                 // 0..7
    const int d0 = blk * 32 + lr, d1 = d0 + 16;
    const float ba0 = bav[d0], ba1 = bav[d1];
    const float bb0 = bbv[d0], bb1 = bbv[d1];
    const float w0 = Wc[d0],  w1 = Wc[d1];

#pragma unroll
    for (int mi = 0; mi < 4; ++mi) {
#pragma unroll
        for (int r = 0; r < 4; ++r) {
            float p = tanhf(acc[mi][0][r] + ba0) * sigf(acc[mi][2][r] + bb0) * w0
                    + tanhf(acc[mi][1][r] + ba1) * sigf(acc[mi][3][r] + bb1) * w1;
            p += __shfl_xor(p, 1); p += __shfl_xor(p, 2);
            p += __shfl_xor(p, 4); p += __shfl_xor(p, 8);
            if (lr == 0)
                ps[(size_t)blk * M_ + m0 + wr * 64 + mi * 16 + lg * 4 + r] = p;
        }
    }
}

// =====================================================================
// K3: fused s-combine + per-slice segmented stats (proven).
// =====================================================================
__global__ __launch_bounds__(256) void sstats_kernel(
    const float* __restrict__ ps, const float* __restrict__ bc,
    const int* __restrict__ cid, float* __restrict__ S,
    float* __restrict__ pst)
{
    __shared__ float redm[4][C_];
    __shared__ float smx[C_];
    __shared__ float reds[4][C_];

    const int b  = blockIdx.x >> 3;
    const int sl = blockIdx.x & 7;
    const int bs = blockIdx.x;
    const int t  = threadIdx.x;
    const int l  = t & 63, wv = t >> 6;
    const int base = b * N_ + sl * 1024;

    float sv[4]; int cv[4];
#pragma unroll
    for (int i = 0; i < 4; ++i) {
        int m = base + i * 256 + t;
        float v = bc[0];
#pragma unroll
        for (int k = 0; k < 8; ++k) v += ps[(size_t)k * M_ + m];
        S[m] = v; sv[i] = v; cv[i] = cid[m];
    }

    float mx[C_];
#pragma unroll
    for (int c = 0; c < C_; ++c) mx[c] = -3.0e38f;
#pragma unroll
    for (int i = 0; i < 4; ++i)
#pragma unroll
        for (int c = 0; c < C_; ++c)
            mx[c] = fmaxf(mx[c], (cv[i] == c) ? sv[i] : -3.0e38f);
#pragma unroll
    for (int c = 0; c < C_; ++c) {
        float v = mx[c];
        v = fmaxf(v, __shfl_xor(v, 32)); v = fmaxf(v, __shfl_xor(v, 16));
        v = fmaxf(v, __shfl_xor(v, 8));  v = fmaxf(v, __shfl_xor(v, 4));
        v = fmaxf(v, __shfl_xor(v, 2));  v = fmaxf(v, __shfl_xor(v, 1));
        if (l == 0) redm[wv][c] = v;
    }
    __syncthreads();
    if (t < C_)
        smx[t] = fmaxf(fmaxf(redm[0][t], redm[1][t]), fmaxf(redm[2][t], redm[3][t]));
    __syncthreads();

    float sm[C_];
#pragma unroll
    for (int c = 0; c < C_; ++c) sm[c] = 0.f;
#pragma unroll
    for (int i = 0; i < 4; ++i) {
        float e = expf(sv[i] - smx[cv[i]]);
#pragma unroll
        for (int c = 0; c < C_; ++c) sm[c] += (cv[i] == c) ? e : 0.f;
    }
#pragma unroll
    for (int c = 0; c < C_; ++c) {
        float v = sm[c];
        v += __shfl_xor(v, 32); v += __shfl_xor(v, 16); v += __shfl_xor(v, 8);
        v += __shfl_xor(v, 4);  v += __shfl_xor(v, 2);  v += __shfl_xor(v, 1);
        if (l == 0) reds[wv][c] = v;
    }
    __syncthreads();
    if (t < C_) {
        pst[bs * C_ + t]       = smx[t];
        pst[640 + bs * C_ + t] = reds[0][t] + reds[1][t] + reds[2][t] + reds[3][t];
    }
}

// =====================================================================
// K4: segmented weighted sums — per-thread private LDS accumulators.
// Thread (half = t>>7, u = t&127): rows [half*64, half*64+64) of the
// 128-row chunk, cols [4u, 4u+4).  Per row: 8B load + ds_read_b128 +
// 4 FMA + ds_write_b128 into acc[c] (runtime c -> LDS, not registers).
// Region stride 44 floats spreads b128 slots across all 32 banks.
// Halves merged through LDS at the end.  ~3x less VALU than the
// 10-way select version.
// =====================================================================
__global__ __launch_bounds__(256) void cpart_kernel(
    const ushort_t* __restrict__ xb, const int* __restrict__ cid,
    const float* __restrict__ s, const float* __restrict__ pst,
    float* __restrict__ cpart)
{
    __shared__ float smax[C_], sinv[C_];
    __shared__ float wrow[128];
    __shared__ int   crow[128];
    __shared__ float accL[256 * 44];   // 45056 B
    const int b     = blockIdx.x >> 6;
    const int chunk = blockIdx.x & 63;
    const int t     = threadIdx.x;
    const int base  = b * N_ + chunk * 128;
    const int u     = t & 127;
    const int half  = t >> 7;

    if (t < C_) {
        float mxv = -3.0e38f;
#pragma unroll
        for (int sl = 0; sl < 8; ++sl)
            mxv = fmaxf(mxv, pst[(b * 8 + sl) * C_ + t]);
        float sum = 0.f;
#pragma unroll
        for (int sl = 0; sl < 8; ++sl)
            sum += pst[640 + (b * 8 + sl) * C_ + t] * expf(pst[(b * 8 + sl) * C_ + t] - mxv);
        smax[t] = mxv;
        sinv[t] = 1.0f / sum;
    }
    float* myacc = &accL[t * 44];
#pragma unroll
    for (int c = 0; c < C_; ++c)
        *(f32x4*)(myacc + c * 4) = (f32x4){0.f, 0.f, 0.f, 0.f};
    __syncthreads();
    if (t < 128) {
        int m = base + t;
        int c = cid[m];
        crow[t] = c;
        wrow[t] = expf(s[m] - smax[c]) * sinv[c];
    }
    __syncthreads();

    const ushort_t* xcol = xb + (size_t)(base + half * 64) * 512 + u * 4;
    for (int r = 0; r < 64; ++r) {
        int rr = half * 64 + r;
        int c = crow[rr];
        float wv = wrow[rr];
        uint2 xv = *(const uint2*)(xcol + (size_t)r * 512);
        f32x4 x4;
        x4[0] = bf2f((ushort_t)(xv.x & 0xffff));
        x4[1] = bf2f((ushort_t)(xv.x >> 16));
        x4[2] = bf2f((ushort_t)(xv.y & 0xffff));
        x4[3] = bf2f((ushort_t)(xv.y >> 16));
        f32x4 a = *(f32x4*)(myacc + c * 4);
        a[0] += wv * x4[0]; a[1] += wv * x4[1];
        a[2] += wv * x4[2]; a[3] += wv * x4[3];
        *(f32x4*)(myacc + c * 4) = a;
    }
    __syncthreads();
    if (half == 0) {
        const float* oacc = &accL[(u + 128) * 44];
#pragma unroll
        for (int c = 0; c < C_; ++c) {
            f32x4 a = *(const f32x4*)(myacc + c * 4);
            f32x4 o = *(const f32x4*)(oacc + c * 4);
            a[0] += o[0]; a[1] += o[1]; a[2] += o[2]; a[3] += o[3];
            *(f32x4*)(&cpart[(((size_t)blockIdx.x) * C_ + c) * 512 + u * 4]) = a;
        }
    }
}

// =====================================================================
// K5: chunk-reduce + intra fc + inter score (proven).
// =====================================================================
__global__ __launch_bounds__(256) void intra_inter_kernel(
    const float* __restrict__ cpart, const float* __restrict__ Wfc,
    const float* __restrict__ bfc,
    const float* __restrict__ Wa2, const float* __restrict__ ba2,
    const float* __restrict__ Wb2, const float* __restrict__ bb2,
    const float* __restrict__ Wc2, const float* __restrict__ bc2,
    float* __restrict__ cfeat2, float* __restrict__ s2)
{
    __shared__ float row[512];
    __shared__ float row2[512];
    __shared__ float red[256];
    const int bc = blockIdx.x;
    const int b = bc / C_, c = bc % C_;
    const int t  = threadIdx.x;

    float r0 = 0.f, r1 = 0.f;
    for (int ch = 0; ch < 64; ++ch) {
        size_t o = (((size_t)(b * 64 + ch)) * C_ + c) * 512;
        r0 += cpart[o + t];
        r1 += cpart[o + 256 + t];
    }
    row[t] = r0; row[t + 256] = r1;
    __syncthreads();

    float a0 = 0.f, a1 = 0.f;
    for (int i = 0; i < 512; ++i) {
        float rv = row[i];
        a0 += rv * Wfc[(size_t)i * 512 + t];
        a1 += rv * Wfc[(size_t)i * 512 + 256 + t];
    }
    a0 = fmaxf(a0 + bfc[t], 0.f);
    a1 = fmaxf(a1 + bfc[256 + t], 0.f);
    cfeat2[bc * 512 + t]       = a0;
    cfeat2[bc * 512 + 256 + t] = a1;
    row2[t] = a0; row2[t + 256] = a1;
    __syncthreads();

    float pa = 0.f, pg = 0.f;
    for (int f = 0; f < 512; ++f) {
        float rv = row2[f];
        pa += rv * Wa2[(size_t)f * 256 + t];
        pg += rv * Wb2[(size_t)f * 256 + t];
    }
    float v = tanhf(pa + ba2[t]) * sigf(pg + bb2[t]) * Wc2[t];
    red[t] = v; __syncthreads();
    for (int off = 128; off > 0; off >>= 1) {
        if (t < off) red[t] += red[t + off];
        __syncthreads();
    }
    if (t == 0) s2[bc] = red[0] + bc2[0];
}

// K6: softmax over C, slide pooling, final fc + classifier
__global__ __launch_bounds__(256) void final_kernel(
    const float* __restrict__ cfeat2, const float* __restrict__ s2,
    const float* __restrict__ Wfc2, const float* __restrict__ bfc2,
    const float* __restrict__ Wcls, const float* __restrict__ bcls,
    float* __restrict__ out)
{
    __shared__ float A2[C_];
    __shared__ float slide[512];
    __shared__ float slide2[256];
    const int b = blockIdx.x;
    const int t = threadIdx.x;

    if (t < C_) A2[t] = s2[b * C_ + t];
    __syncthreads();
    float mx = -3.0e38f;
    for (int c = 0; c < C_; ++c) mx = fmaxf(mx, A2[c]);
    float sum = 0.f;
    for (int c = 0; c < C_; ++c) sum += expf(A2[c] - mx);
    __syncthreads();
    if (t < C_) A2[t] = expf(A2[t] - mx) / sum;
    __syncthreads();

    float s0 = 0.f, s1 = 0.f;
    for (int c = 0; c < C_; ++c) {
        float a = A2[c];
        s0 += a * cfeat2[(b * C_ + c) * 512 + t];
        s1 += a * cfeat2[(b * C_ + c) * 512 + 256 + t];
    }
    slide[t] = s0; slide[t + 256] = s1;
    __syncthreads();

    float acc = 0.f;
    for (int f = 0; f < 512; ++f) acc += slide[f] * Wfc2[(size_t)f * 256 + t];
    slide2[t] = fmaxf(acc + bfc2[t], 0.f);
    __syncthreads();

    if (t < NCLS_) {
        float lg = bcls[t];
        for (int o = 0; o < 256; ++o) lg += slide2[o] * Wcls[o * 2 + t];
        out[b * 2 + t] = lg;
    }
}

extern "C" void kernel_launch(void* const* d_in, const int* in_sizes, int n_in,
                              void* d_out, int out_size, void* d_ws, size_t ws_size,
                              hipStream_t stream)
{
    (void)in_sizes; (void)n_in; (void)out_size; (void)ws_size;
    const float* h    = (const float*)d_in[0];
    const int*   cid  = (const int*)  d_in[1];
    const float* emb  = (const float*)d_in[2];
    const float* Wf   = (const float*)d_in[3];
    const float* bf   = (const float*)d_in[4];
    const float* Wa   = (const float*)d_in[5];
    const float* ba   = (const float*)d_in[6];
    const float* Wb   = (const float*)d_in[7];
    const float* bb   = (const float*)d_in[8];
    const float* Wc   = (const float*)d_in[9];
    const float* bc   = (const float*)d_in[10];
    const float* Wfc  = (const float*)d_in[11];
    const float* bfc  = (const float*)d_in[12];
    const float* Wa2  = (const float*)d_in[13];
    const float* ba2  = (const float*)d_in[14];
    const float* Wb2  = (const float*)d_in[15];
    const float* bb2  = (const float*)d_in[16];
    const float* Wc2  = (const float*)d_in[17];
    const float* bc2  = (const float*)d_in[18];
    const float* Wfc2 = (const float*)d_in[19];
    const float* bfc2 = (const float*)d_in[20];
    const float* Wcls = (const float*)d_in[21];
    const float* bcls = (const float*)d_in[22];

    char* ws = (char*)d_ws;
    ushort_t* XB   = (ushort_t*)(ws + XB_OFF);
    float* PS      = (float*)(ws + PS_OFF);
    float* S       = (float*)(ws + S_OFF);
    float* PST     = (float*)(ws + PST_OFF);
    float* CPART   = (float*)(ws + CP_OFF);
    float* CFEAT2  = (float*)(ws + CF2_OFF);
    float* S2      = (float*)(ws + S2_OFF);
    ushort_t* WFT  = (ushort_t*)(ws + WFT_OFF);
    ushort_t* BAG  = (ushort_t*)(ws + BAG_OFF);
    float* EMBW    = (float*)(ws + EMBW_OFF);
    float* out     = (float*)d_out;

    prep_kernel<<<596, 256, 0, stream>>>(Wf, Wa, Wb, emb, bf, WFT, BAG, EMBW);

    gemm_x_mfma<<<dim3(4, 256), 512, 0, stream>>>(h, cid, WFT, EMBW, XB);
    gemm_ag_mfma<<<dim3(4, 256), 512, 0, stream>>>(XB, BAG, ba, bb, Wc, PS);

    sstats_kernel<<<64, 256, 0, stream>>>(PS, bc, cid, S, PST);
    cpart_kernel<<<512, 256, 0, stream>>>(XB, cid, S, PST, CPART);
    intra_inter_kernel<<<B_ * C_, 256, 0, stream>>>(CPART, Wfc, bfc,
                                                    Wa2, ba2, Wb2, bb2, Wc2, bc2,
                                                    CFEAT2, S2);
    final_kernel<<<B_, 256, 0, stream>>>(CFEAT2, S2, Wfc2, bfc2, Wcls, bcls, out);
}